// Round 5
// baseline (1203.744 us; speedup 1.0000x reference)
//
#include <hip/hip_runtime.h>

constexpr int D_  = 1024;  // embedding dim
constexpr int E_  = 64;    // experts
constexpr int N_  = 1024;  // B*S tokens
constexpr int TG  = 32;    // tokens per pass
constexpr int CS  = 32;    // column slices (blocks per expert)
constexpr int CPB = D_ / CS;   // 32 cols per block (1 col per thread)
constexpr int KG  = 8;     // k-groups (tid>>5)
constexpr int KR  = D_ / KG;   // 128 k-rows per group
constexpr int DC  = 16;    // w-panel rows per chunk (in registers)
constexpr int NC  = KR / DC;   // 8 chunks

// One block = (col-slice cs, expert e). 256 threads = 8 k-groups x 32 cols.
// Steady-state loop has ZERO barriers: w double-buffered in registers
// (nontemporal, trans streamed from HBM exactly once), x read directly from
// L1/L2 (uniform per 32-lane group -> broadcast). Barriers only in bucketing
// and the per-pass reduce epilogue, so the load pipe never drains mid-K.
__global__ __launch_bounds__(256, 4) void fused_moe_kernel(
    const float* __restrict__ x, const int* __restrict__ urls,
    const float* __restrict__ trans, const float* __restrict__ bias,
    float* __restrict__ out) {
  __shared__ __align__(16) int toksL[N_];  // 4 KB
  __shared__ float red[KG][8][33];         // 8.25 KB, pad 33: conflict-free
  __shared__ int cntS;

  const int tid = threadIdx.x;
  const int cs  = blockIdx.x;
  const int e   = blockIdx.y;
  const int kg  = tid >> 5;   // 0..7
  const int ct  = tid & 31;   // 0..31
  const int c0  = cs * CPB;

  // ---- in-block bucketing ----
  for (int i = tid; i < N_; i += 256) toksL[i] = 0;  // safe padding for tail quads
  if (tid == 0) cntS = 0;
  __syncthreads();
  for (int i = tid; i < N_; i += 256) {
    if (urls[i] == e) { int p = atomicAdd(&cntS, 1); toksL[p] = i; }
  }
  __syncthreads();
  const int Ttot = cntS;

  const float* __restrict__ tr = trans + (size_t)e * D_ * D_ + c0 + ct;  // this thread's col
  const int kbase0 = kg * KR;

  for (int beg = 0; beg < Ttot; beg += TG) {
    const int T     = (Ttot - beg < TG) ? (Ttot - beg) : TG;
    const int nQuad = (T + 3) >> 2;

    float acc[TG];
#pragma unroll
    for (int t = 0; t < TG; ++t) acc[t] = 0.f;

    float w0[DC], w1[DC];

    auto loadW = [&](float (&w)[DC], int c) {
#pragma unroll
      for (int r = 0; r < DC; ++r)
        w[r] = __builtin_nontemporal_load(&tr[(size_t)(kbase0 + c * DC + r) * D_]);
    };

    auto compute = [&](const float (&w)[DC], int c) {
      const int kb = kbase0 + c * DC;
#pragma unroll
      for (int q = 0; q < TG / 4; ++q) {
        if (q < nQuad) {  // uniform branch: skip empty token quads
          const int4 tk4 = *(const int4*)&toksL[beg + q * 4];
#pragma unroll
          for (int j = 0; j < 4; ++j) {
            const int tk = (j == 0) ? tk4.x : (j == 1) ? tk4.y : (j == 2) ? tk4.z : tk4.w;
            const float* xp = x + (size_t)tk * D_ + kb;  // uniform per 32-lane group
            const float4 a0 = *(const float4*)(xp + 0);
            const float4 a1 = *(const float4*)(xp + 4);
            const float4 a2 = *(const float4*)(xp + 8);
            const float4 a3 = *(const float4*)(xp + 12);
            float s = acc[q * 4 + j];
            s += a0.x * w[0]  + a0.y * w[1]  + a0.z * w[2]  + a0.w * w[3];
            s += a1.x * w[4]  + a1.y * w[5]  + a1.z * w[6]  + a1.w * w[7];
            s += a2.x * w[8]  + a2.y * w[9]  + a2.z * w[10] + a2.w * w[11];
            s += a3.x * w[12] + a3.y * w[13] + a3.z * w[14] + a3.w * w[15];
            acc[q * 4 + j] = s;
          }
        }
      }
    };

    // software-pipelined, barrier-free K loop (NC = 8, manual 2x unroll,
    // all w indices compile-time -> registers, never scratch)
    loadW(w0, 0);
#pragma unroll
    for (int c = 0; c < NC; c += 2) {
      loadW(w1, c + 1);
      compute(w0, c);
      if (c + 2 < NC) loadW(w0, c + 2);
      compute(w1, c + 1);
    }

    // ---- reduce across k-groups + bias + tanh + store (4 rounds x 8 tokens) ----
    const int tt_r = tid >> 5;  // token-in-round 0..7
    const int ct_r = tid & 31;
#pragma unroll
    for (int r = 0; r < 4; ++r) {
      __syncthreads();  // red free (prev round's reads / prev pass done)
#pragma unroll
      for (int tt = 0; tt < 8; ++tt)
        red[kg][tt][ct] = acc[r * 8 + tt];
      __syncthreads();
      const int slot = r * 8 + tt_r;
      if (slot < T) {
        float s = 0.f;
#pragma unroll
        for (int g = 0; g < KG; ++g) s += red[g][tt_r][ct_r];
        const int tok = toksL[beg + slot];
        const float b = bias[(size_t)e * D_ + c0 + ct_r];  // urls[tok] == e here
        out[(size_t)tok * D_ + c0 + ct_r] = tanhf(s + b);
      }
    }
  }
}

extern "C" void kernel_launch(void* const* d_in, const int* in_sizes, int n_in,
                              void* d_out, int out_size, void* d_ws, size_t ws_size,
                              hipStream_t stream) {
  const float* x     = (const float*)d_in[0];
  const int*   urls  = (const int*)d_in[1];
  const float* trans = (const float*)d_in[2];
  const float* bias  = (const float*)d_in[3];
  float* out = (float*)d_out;

  dim3 grid(CS, E_);
  fused_moe_kernel<<<grid, 256, 0, stream>>>(x, urls, trans, bias, out);
}